// Round 11
// baseline (285.148 us; speedup 1.0000x reference)
//
#include <hip/hip_runtime.h>

// TV Chambolle, image (8, 2048, 128) f32: 29 p-updates + final out = x + div(p) + bias.
// v = b*SB + t*ST + f.
//
// R11 = R10 (first(1+4) + 5 x mid(4) + last(4+epilogue) = 29 iters, 7 dispatches)
// with k_last's register spill fixed: R10's k_last (EE=18, GR=9) kept 180 floats
// of state -> memory scratch spill (WRITE_SIZE 33 MB = 8 out + 25 scratch).
// k_last now drops the Xr preload array (template XR=false): x is reloaded from
// L1/L2 per row inside phase_out and the epilogue (R7-proven pattern). State
// 180 -> 144 floats. k_first/k_mid keep the proven XR=true path unchanged.

#define BB 8
#define TT 2048
#define FF 128
#define NV (BB*TT*FF)        // 2,097,152
#define SB (TT*FF)           // 262144
#define ST FF                // 128
#define RR 8                 // owned t-rows per block
#define NBLK (TT/RR)         // 256

constexpr float TAU = 1.0f / 6.0f;

__device__ __forceinline__ float4 ld4(const float* p) { return *reinterpret_cast<const float4*>(p); }
__device__ __forceinline__ void st4(float* p, const float4& v) { *reinterpret_cast<float4*>(p) = v; }
__device__ __forceinline__ float4 shfl_up4(float4 v, int d) {
    return make_float4(__shfl_up(v.x, d), __shfl_up(v.y, d), __shfl_up(v.z, d), __shfl_up(v.w, d));
}
__device__ __forceinline__ float4 shfl_dn4(float4 v, int d) {
    return make_float4(__shfl_down(v.x, d), __shfl_down(v.y, d), __shfl_down(v.z, d), __shfl_down(v.w, d));
}
__device__ __forceinline__ float4 sub4(const float4& a, const float4& b) {
    return make_float4(a.x - b.x, a.y - b.y, a.z - b.z, a.w - b.w);
}
__device__ __forceinline__ float4 f4z() { return make_float4(0.f, 0.f, 0.f, 0.f); }
// 1/(|g|*s + 1) elementwise; v_sqrt_f32 + v_rcp_f32 approx (12x tolerance headroom,
// sqrt(0)=0 keeps the zero-gradient corner exact).
__device__ __forceinline__ float4 nbvec(const float4& gB, const float4& gT, const float4& gF, float s) {
    float4 nb; float q;
    q = gB.x * gB.x + gT.x * gT.x + gF.x * gF.x;
    nb.x = __builtin_amdgcn_rcpf(fmaf(__builtin_amdgcn_sqrtf(q), s, 1.f));
    q = gB.y * gB.y + gT.y * gT.y + gF.y * gF.y;
    nb.y = __builtin_amdgcn_rcpf(fmaf(__builtin_amdgcn_sqrtf(q), s, 1.f));
    q = gB.z * gB.z + gT.z * gT.z + gF.z * gF.z;
    nb.z = __builtin_amdgcn_rcpf(fmaf(__builtin_amdgcn_sqrtf(q), s, 1.f));
    q = gB.w * gB.w + gT.w * gT.w + gF.w * gF.w;
    nb.w = __builtin_amdgcn_rcpf(fmaf(__builtin_amdgcn_sqrtf(q), s, 1.f));
    return nb;
}

struct ConeShared {                      // sized for max EE=18; ~12.6 KB
    float p2b[18][4][8];                 // p2.w at fg==7 per [row][w][b]
    float outx[18][4][8];                // out.x at fg==0 per [row][w][b]
    float4 p1if[256];                    // group0's P1[row GR-1] per column
    float4 oif[256];                     // group1's O[row GR]   per column
};

// ---- cone phases, templated on EE and row-group (no barriers inside) ----
template<int EEt, int RG>
__device__ __forceinline__ void publish(int k, float4 (&P1)[EEt/2], float4 (&P2)[EEt/2],
                                        ConeShared& sh, int c, int b, int fg, int w) {
    constexpr int GRt = EEt / 2;
    if (fg == 7) {
        #pragma unroll
        for (int le = 0; le < GRt; ++le) {
            const int e = RG * GRt + le;
            if (e >= k && e < EEt - k) sh.p2b[e][w][b] = P2[le].w;
        }
    }
    if (RG == 0) sh.p1if[c] = P1[GRt - 1];
}

// XR=true: X from preloaded Xr registers. XR=false: X reloaded from x (L1/L2 hit)
// to keep per-thread state under the arch-VGPR budget (k_last, GR=9).
template<int EEt, int RG, bool ELO, bool EHI, bool XR>
__device__ __forceinline__ void phase_out(
    int k, const float* __restrict__ x, int base, const float4* Xr,
    float4 (&P0)[EEt/2], float4 (&P1)[EEt/2], float4 (&P2)[EEt/2], float4 (&O)[EEt/2],
    ConeShared& sh, int c, int b, int fg, int w, int f0, int tb) {
    constexpr int GRt = EEt / 2;
    #pragma unroll
    for (int le = 0; le < GRt; ++le) {
        const int e = RG * GRt + le;
        if (e < k + 1 || e >= EEt - k) continue;         // compile-time row kill
        const int t = tb + e;
        if ((ELO && t < 0) || (EHI && t >= TT)) continue;
        const float4 X = XR ? Xr[le] : ld4(x + base + t * ST);
        float4 o;
        o.x = X.x - P0[le].x - P1[le].x - P2[le].x;
        o.y = X.y - P0[le].y - P1[le].y - P2[le].y + P2[le].x;
        o.z = X.z - P0[le].z - P1[le].z - P2[le].z + P2[le].y;
        o.w = X.w - P0[le].w - P1[le].w - P2[le].w + P2[le].z;
        float4 h0 = shfl_up4(P0[le], 1);                 // p0 at b-1
        if (b > 0) { o.x += h0.x; o.y += h0.y; o.z += h0.z; o.w += h0.w; }
        float4 pm1 = (le > 0) ? P1[le - 1] : sh.p1if[c]; // p1 at t-1 (LDS only RG1,le0)
        if (!ELO || t > 0) { o.x += pm1.x; o.y += pm1.y; o.z += pm1.z; o.w += pm1.w; }
        float pw = __shfl_up(P2[le].w, 8);               // p2.w at f0-4
        if (fg == 0) pw = (w > 0) ? sh.p2b[e][(w - 1)][b] : 0.0f;
        if (f0 > 0) o.x += pw;
        O[le] = o;
        if (fg == 0) sh.outx[e][w][b] = o.x;
    }
}

template<int EEt, int RG, bool ELO, bool EHI>
__device__ __forceinline__ void phase_upd(
    int k, float4 (&P0)[EEt/2], float4 (&P1)[EEt/2], float4 (&P2)[EEt/2], float4 (&O)[EEt/2],
    ConeShared& sh, int c, int b, int fg, int w, int f0, int tb, float s) {
    constexpr int GRt = EEt / 2;
    #pragma unroll
    for (int le = 0; le < GRt; ++le) {
        const int e = RG * GRt + le;
        if (e < k + 1 || e > EEt - 2 - k) continue;      // compile-time row kill
        const int t = tb + e;
        if ((ELO && t < 0) || (EHI && t >= TT)) continue;
        const float4 cc = O[le];
        const float4 on = (le < GRt - 1) ? O[le + 1] : sh.oif[c];  // oif only RG0,le=GRt-1
        float4 gT = f4z();
        if (!EHI || t < TT - 1) gT = sub4(on, cc);
        const float4 nB = shfl_dn4(cc, 1);               // out at b+1
        float4 gB = f4z();
        if (b < BB - 1) gB = sub4(nB, cc);
        float nxx = __shfl_down(cc.x, 8);                // out.x at f0+4
        if (fg == 7) nxx = (w < 3) ? sh.outx[e][w + 1][b] : 0.0f;
        float4 gF;
        gF.x = cc.y - cc.x;
        gF.y = cc.z - cc.y;
        gF.z = cc.w - cc.z;
        gF.w = (f0 < FF - 4) ? (nxx - cc.w) : 0.f;
        const float4 nb = nbvec(gB, gT, gF, s);
        P0[le].x = fmaf(-TAU, gB.x, P0[le].x) * nb.x;
        P0[le].y = fmaf(-TAU, gB.y, P0[le].y) * nb.y;
        P0[le].z = fmaf(-TAU, gB.z, P0[le].z) * nb.z;
        P0[le].w = fmaf(-TAU, gB.w, P0[le].w) * nb.w;
        P1[le].x = fmaf(-TAU, gT.x, P1[le].x) * nb.x;
        P1[le].y = fmaf(-TAU, gT.y, P1[le].y) * nb.y;
        P1[le].z = fmaf(-TAU, gT.z, P1[le].z) * nb.z;
        P1[le].w = fmaf(-TAU, gT.w, P1[le].w) * nb.w;
        P2[le].x = fmaf(-TAU, gF.x, P2[le].x) * nb.x;
        P2[le].y = fmaf(-TAU, gF.y, P2[le].y) * nb.y;
        P2[le].z = fmaf(-TAU, gF.z, P2[le].z) * nb.z;
        P2[le].w = fmaf(-TAU, gF.w, P2[le].w) * nb.w;
    }
}

// barriers live here, block-uniform; rg branches wrap only barrier-free compute
template<int EEt, int HHt, bool ELO, bool EHI, bool XR>
__device__ __forceinline__ void cone_run(
    const float* __restrict__ x, int base, const float4* Xr,
    float4 (&P0)[EEt/2], float4 (&P1)[EEt/2], float4 (&P2)[EEt/2], float4 (&O)[EEt/2],
    ConeShared& sh, int rg, int c, int b, int fg, int w, int f0, int tb, float s) {
    #pragma unroll
    for (int k = 0; k < HHt; ++k) {
        if (rg == 0) publish<EEt, 0>(k, P1, P2, sh, c, b, fg, w);
        else         publish<EEt, 1>(k, P1, P2, sh, c, b, fg, w);
        __syncthreads();
        if (rg == 0) phase_out<EEt, 0, ELO, EHI, XR>(k, x, base, Xr, P0, P1, P2, O, sh, c, b, fg, w, f0, tb);
        else         phase_out<EEt, 1, ELO, EHI, XR>(k, x, base, Xr, P0, P1, P2, O, sh, c, b, fg, w, f0, tb);
        if (rg == 1) sh.oif[c] = O[0];                   // out at row GRt
        __syncthreads();
        if (rg == 0) phase_upd<EEt, 0, ELO, EHI>(k, P0, P1, P2, O, sh, c, b, fg, w, f0, tb, s);
        else         phase_upd<EEt, 1, ELO, EHI>(k, P0, P1, P2, O, sh, c, b, fg, w, f0, tb, s);
    }
}

// ==================== mid launch: 4 cone iterations (EE=16, M=4) ====================
template<bool ELO, bool EHI>
__device__ __forceinline__ void mid_main(
    const float* __restrict__ x, const float* __restrict__ pin, float* __restrict__ pout,
    ConeShared& sh, int rg, int c, int b, int fg, int w, int f0, int tb, int e0,
    int base, float s) {
    constexpr int GRt = 8;
    float4 P0[GRt], P1[GRt], P2[GRt], O[GRt], Xr[GRt];
    #pragma unroll
    for (int le = 0; le < GRt; ++le) {
        const int t = tb + e0 + le;
        const bool ok = (!ELO || t >= 0) && (!EHI || t < TT);
        const bool trim = (rg == 0 && le == 0);          // row 0: only P1 ever read
        if (ok) {
            const int v = base + t * ST;
            P1[le] = ld4(pin + NV + v);
            if (!trim) {
                P0[le] = ld4(pin + v);
                P2[le] = ld4(pin + 2 * NV + v);
                Xr[le] = ld4(x + v);
            } else { P0[le] = f4z(); P2[le] = f4z(); Xr[le] = f4z(); }
        } else {
            P0[le] = f4z(); P1[le] = f4z(); P2[le] = f4z(); Xr[le] = f4z();
        }
        O[le] = f4z();
    }
    cone_run<16, 4, ELO, EHI, true>(x, base, Xr, P0, P1, P2, O, sh, rg, c, b, fg, w, f0, tb, s);
    #pragma unroll
    for (int le = 0; le < GRt; ++le) {
        const int e = e0 + le;
        if (e >= 4 && e < 12) {                          // owned rows: t always valid
            const int v = base + (tb + e) * ST;
            st4(pout + v, P0[le]);
            st4(pout + NV + v, P1[le]);
            st4(pout + 2 * NV + v, P2[le]);
        }
    }
}

__global__ __launch_bounds__(512, 2)
void k_mid(const float* __restrict__ x, const float* __restrict__ pin,
           float* __restrict__ pout, const float* __restrict__ lam) {
    __shared__ ConeShared sh;
    const int tid = threadIdx.x;
    const int blk = blockIdx.x;
    const int rg  = tid >> 8;
    const int c   = tid & 255;
    const int b   = tid & 7;
    const int fg  = (tid >> 3) & 7;
    const int w   = (tid >> 6) & 3;
    const int f0  = w * 32 + fg * 4;
    const int tb  = blk * RR - 4;
    const int e0  = rg * 8;
    const int base = b * SB + f0;
    const float s = TAU / lam[0];
    if (blk == 0 || blk == NBLK - 1)
        mid_main<true, true>(x, pin, pout, sh, rg, c, b, fg, w, f0, tb, e0, base, s);
    else
        mid_main<false, false>(x, pin, pout, sh, rg, c, b, fg, w, f0, tb, e0, base, s);
}

// ============ first launch: iter 1 from p==0 (out==x) + 4 cone iters (EE=16) ============
template<bool ELO, bool EHI>
__device__ __forceinline__ void first_main(
    const float* __restrict__ x, float* __restrict__ pout,
    ConeShared& sh, int rg, int c, int b, int fg, int w, int f0, int tb, int e0,
    int base, float s) {
    constexpr int GRt = 8;
    float4 P0[GRt], P1[GRt], P2[GRt], O[GRt], Xr[GRt], XHa;
    #pragma unroll
    for (int le = 0; le < GRt; ++le) {
        const int t = tb + e0 + le;
        const bool ok = (!ELO || t >= 0) && (!EHI || t < TT);
        Xr[le] = ok ? ld4(x + base + t * ST) : f4z();
        O[le] = f4z();
    }
    {
        const int t = tb + e0 + GRt;
        const bool ok = (!ELO || t >= 0) && (t < TT);
        XHa = ok ? ld4(x + base + t * ST) : f4z();
    }
    // iteration 1: p = -TAU*grad(x) / (|grad(x)|*s + 1) on all valid rows
    #pragma unroll
    for (int le = 0; le < GRt; ++le) {
        const int t = tb + e0 + le;
        if ((!ELO || t >= 0) && (!EHI || t < TT)) {
            const float4 cc = Xr[le];
            const float4 nxt = (le < GRt - 1) ? Xr[le + 1] : XHa;
            float4 gT = f4z();
            if (t < TT - 1) gT = sub4(nxt, cc);
            const float4 nB = shfl_dn4(cc, 1);
            float4 gB = f4z();
            if (b < BB - 1) gB = sub4(nB, cc);
            float4 gF;
            gF.x = cc.y - cc.x;
            gF.y = cc.z - cc.y;
            gF.z = cc.w - cc.z;
            gF.w = (f0 < FF - 4) ? (x[base + t * ST + 4] - cc.w) : 0.f;
            const float4 nb = nbvec(gB, gT, gF, s);
            P0[le] = make_float4(-TAU * gB.x * nb.x, -TAU * gB.y * nb.y,
                                 -TAU * gB.z * nb.z, -TAU * gB.w * nb.w);
            P1[le] = make_float4(-TAU * gT.x * nb.x, -TAU * gT.y * nb.y,
                                 -TAU * gT.z * nb.z, -TAU * gT.w * nb.w);
            P2[le] = make_float4(-TAU * gF.x * nb.x, -TAU * gF.y * nb.y,
                                 -TAU * gF.z * nb.z, -TAU * gF.w * nb.w);
        } else {
            P0[le] = f4z(); P1[le] = f4z(); P2[le] = f4z();
        }
    }
    cone_run<16, 4, ELO, EHI, true>(x, base, Xr, P0, P1, P2, O, sh, rg, c, b, fg, w, f0, tb, s);
    #pragma unroll
    for (int le = 0; le < GRt; ++le) {
        const int e = e0 + le;
        if (e >= 4 && e < 12) {
            const int v = base + (tb + e) * ST;
            st4(pout + v, P0[le]);
            st4(pout + NV + v, P1[le]);
            st4(pout + 2 * NV + v, P2[le]);
        }
    }
}

__global__ __launch_bounds__(512, 2)
void k_first(const float* __restrict__ x, float* __restrict__ pout,
             const float* __restrict__ lam) {
    __shared__ ConeShared sh;
    const int tid = threadIdx.x;
    const int blk = blockIdx.x;
    const int rg  = tid >> 8;
    const int c   = tid & 255;
    const int b   = tid & 7;
    const int fg  = (tid >> 3) & 7;
    const int w   = (tid >> 6) & 3;
    const int f0  = w * 32 + fg * 4;
    const int tb  = blk * RR - 4;
    const int e0  = rg * 8;
    const int base = b * SB + f0;
    const float s = TAU / lam[0];
    if (blk == 0 || blk == NBLK - 1)
        first_main<true, true>(x, pout, sh, rg, c, b, fg, w, f0, tb, e0, base, s);
    else
        first_main<false, false>(x, pout, sh, rg, c, b, fg, w, f0, tb, e0, base, s);
}

// ======== last launch: 4 cone iters (EE=18, M=5) + fused out = x + div(p) + bias ========
// XR=false: no Xr array (state 180 -> 144 floats; R10's GR=9 Xr preload memory-spilled).
template<bool ELO, bool EHI>
__device__ __forceinline__ void last_main(
    const float* __restrict__ x, const float* __restrict__ pin,
    const float* __restrict__ bias, float* __restrict__ out,
    ConeShared& sh, int rg, int c, int b, int fg, int w, int f0, int tb, int e0,
    int base, float s) {
    constexpr int GRt = 9;
    float4 P0[GRt], P1[GRt], P2[GRt], O[GRt];
    #pragma unroll
    for (int le = 0; le < GRt; ++le) {
        const int t = tb + e0 + le;
        const bool ok = (!ELO || t >= 0) && (!EHI || t < TT);
        const bool trim = (rg == 0 && le == 0);
        if (ok) {
            const int v = base + t * ST;
            P1[le] = ld4(pin + NV + v);
            if (!trim) {
                P0[le] = ld4(pin + v);
                P2[le] = ld4(pin + 2 * NV + v);
            } else { P0[le] = f4z(); P2[le] = f4z(); }
        } else {
            P0[le] = f4z(); P1[le] = f4z(); P2[le] = f4z();
        }
        O[le] = f4z();
    }
    cone_run<18, 4, ELO, EHI, false>(x, base, nullptr, P0, P1, P2, O, sh, rg, c, b, fg, w, f0, tb, s);
    // after 4 updates: rows [4,13] exact. Epilogue out rows [5,13).
    if (rg == 0) publish<18, 0>(4, P1, P2, sh, c, b, fg, w);   // k=4 guard covers [4,14)
    else         publish<18, 1>(4, P1, P2, sh, c, b, fg, w);
    __syncthreads();
    const float4 bi = ld4(bias + f0);
    #pragma unroll
    for (int le = 0; le < GRt; ++le) {
        const int e = e0 + le;
        if (e < 5 || e >= 13) continue;                  // epilogue rows only
        const int t = tb + e;                            // always in [0, TT)
        const float4 X = ld4(x + base + t * ST);         // L1/L2 hit
        float4 o;
        o.x = X.x - P0[le].x - P1[le].x - P2[le].x;
        o.y = X.y - P0[le].y - P1[le].y - P2[le].y + P2[le].x;
        o.z = X.z - P0[le].z - P1[le].z - P2[le].z + P2[le].y;
        o.w = X.w - P0[le].w - P1[le].w - P2[le].w + P2[le].z;
        float4 h0 = shfl_up4(P0[le], 1);                 // p0 at b-1
        if (b > 0) { o.x += h0.x; o.y += h0.y; o.z += h0.z; o.w += h0.w; }
        float4 pm1 = (le > 0) ? P1[le - 1] : sh.p1if[c]; // p1 at t-1 (LDS: rg1,le0)
        if (!ELO || t > 0) { o.x += pm1.x; o.y += pm1.y; o.z += pm1.z; o.w += pm1.w; }
        float pw = __shfl_up(P2[le].w, 8);               // p2.w at f0-4
        if (fg == 0) pw = (w > 0) ? sh.p2b[e][w - 1][b] : 0.0f;
        if (f0 > 0) o.x += pw;
        o.x += bi.x; o.y += bi.y; o.z += bi.z; o.w += bi.w;
        st4(out + base + t * ST, o);
    }
}

__global__ __launch_bounds__(512, 2)
void k_last(const float* __restrict__ x, const float* __restrict__ pin,
            const float* __restrict__ bias, float* __restrict__ out,
            const float* __restrict__ lam) {
    __shared__ ConeShared sh;
    const int tid = threadIdx.x;
    const int blk = blockIdx.x;
    const int rg  = tid >> 8;
    const int c   = tid & 255;
    const int b   = tid & 7;
    const int fg  = (tid >> 3) & 7;
    const int w   = (tid >> 6) & 3;
    const int f0  = w * 32 + fg * 4;
    const int tb  = blk * RR - 5;                        // margin M=5
    const int e0  = rg * 9;
    const int base = b * SB + f0;
    const float s = TAU / lam[0];
    if (blk == 0 || blk == NBLK - 1)
        last_main<true, true>(x, pin, bias, out, sh, rg, c, b, fg, w, f0, tb, e0, base, s);
    else
        last_main<false, false>(x, pin, bias, out, sh, rg, c, b, fg, w, f0, tb, e0, base, s);
}

extern "C" void kernel_launch(void* const* d_in, const int* in_sizes, int n_in,
                              void* d_out, int out_size, void* d_ws, size_t ws_size,
                              hipStream_t stream) {
    const float* x    = (const float*)d_in[0];
    const float* lam  = (const float*)d_in[1];
    const float* bias = (const float*)d_in[2];
    float* out = (float*)d_out;

    float* pA = (float*)d_ws;
    float* pB = pA + 3 * NV;

    // iterations 1..5 (iter-1 specialization + 4 cone iters)
    k_first<<<NBLK, 512, 0, stream>>>(x, pA, lam);
    // iterations 6..25: 5 launches x 4
    float* pin = pA;
    float* pout = pB;
    for (int i = 0; i < 5; ++i) {
        k_mid<<<NBLK, 512, 0, stream>>>(x, pin, pout, lam);
        float* tmp = pin; pin = pout; pout = tmp;
    }
    // iterations 26..29 + fused out = x + div(p) + bias
    k_last<<<NBLK, 512, 0, stream>>>(x, pin, bias, out, lam);
}

// Round 12
// 255.882 us; speedup vs baseline: 1.1144x; 1.1144x over previous
//
#include <hip/hip_runtime.h>
#include <hip/hip_fp16.h>

// TV Chambolle, image (8, 2048, 128) f32: 29 p-updates + final out = x + div(p) + bias.
// v = b*SB + t*ST + f.
//
// R12 = R8 schedule (first(1+4) + 6 x mid(4) + k_final = 29 iters, 8 dispatches;
// the R10/R11 fused-last with GR=9 is abandoned -- it memory-spills at any
// register budget) with p stored between launches as PACKED fp16:
//  - compute stays fp32 in registers; only the inter-launch p format is half.
//  - per mid launch: p read 49->24.5 MB (cone reads p twice), write 24.5->12.3 MB.
//  - tolerance headroom 12x; fp16 rounding through 7 round-trips of a
//    non-expansive iteration adds ~5e-3 absolute (threshold 0.0956).
// Cone: RR=8, HH=4, EE=16, 2 row-groups, 512-thr blocks, (512,2), folded guards,
// edge/interior specialization, 2 barriers/iter, approx rcp/sqrt.

#define BB 8
#define TT 2048
#define FF 128
#define NV (BB*TT*FF)        // 2,097,152
#define SB (TT*FF)           // 262144
#define ST FF                // 128
#define RR 8                 // owned t-rows per block
#define NBLK (TT/RR)         // 256
#define HH 4                 // cone iterations per launch
#define EE 16                // extended rows
#define GR 8                 // rows per row-group

constexpr float TAU = 1.0f / 6.0f;

__device__ __forceinline__ float4 ld4(const float* p) { return *reinterpret_cast<const float4*>(p); }
__device__ __forceinline__ void st4(float* p, const float4& v) { *reinterpret_cast<float4*>(p) = v; }
// packed fp16 <-> fp32x4 (8-byte transactions)
__device__ __forceinline__ float4 ld4h(const __half* p) {
    uint2 u = *reinterpret_cast<const uint2*>(p);
    __half2 h0 = *reinterpret_cast<__half2*>(&u.x);
    __half2 h1 = *reinterpret_cast<__half2*>(&u.y);
    float2 a = __half22float2(h0), b2 = __half22float2(h1);
    return make_float4(a.x, a.y, b2.x, b2.y);
}
__device__ __forceinline__ void st4h(__half* p, const float4& v) {
    __half2 h0 = __float22half2_rn(make_float2(v.x, v.y));
    __half2 h1 = __float22half2_rn(make_float2(v.z, v.w));
    uint2 u;
    u.x = *reinterpret_cast<unsigned*>(&h0);
    u.y = *reinterpret_cast<unsigned*>(&h1);
    *reinterpret_cast<uint2*>(p) = u;
}
__device__ __forceinline__ float4 shfl_up4(float4 v, int d) {
    return make_float4(__shfl_up(v.x, d), __shfl_up(v.y, d), __shfl_up(v.z, d), __shfl_up(v.w, d));
}
__device__ __forceinline__ float4 shfl_dn4(float4 v, int d) {
    return make_float4(__shfl_down(v.x, d), __shfl_down(v.y, d), __shfl_down(v.z, d), __shfl_down(v.w, d));
}
__device__ __forceinline__ float4 sub4(const float4& a, const float4& b) {
    return make_float4(a.x - b.x, a.y - b.y, a.z - b.z, a.w - b.w);
}
__device__ __forceinline__ float4 f4z() { return make_float4(0.f, 0.f, 0.f, 0.f); }
// 1/(|g|*s + 1) elementwise; v_sqrt_f32 + v_rcp_f32 approx (12x tolerance headroom,
// sqrt(0)=0 keeps the zero-gradient corner exact).
__device__ __forceinline__ float4 nbvec(const float4& gB, const float4& gT, const float4& gF, float s) {
    float4 nb; float q;
    q = gB.x * gB.x + gT.x * gT.x + gF.x * gF.x;
    nb.x = __builtin_amdgcn_rcpf(fmaf(__builtin_amdgcn_sqrtf(q), s, 1.f));
    q = gB.y * gB.y + gT.y * gT.y + gF.y * gF.y;
    nb.y = __builtin_amdgcn_rcpf(fmaf(__builtin_amdgcn_sqrtf(q), s, 1.f));
    q = gB.z * gB.z + gT.z * gT.z + gF.z * gF.z;
    nb.z = __builtin_amdgcn_rcpf(fmaf(__builtin_amdgcn_sqrtf(q), s, 1.f));
    q = gB.w * gB.w + gT.w * gT.w + gF.w * gF.w;
    nb.w = __builtin_amdgcn_rcpf(fmaf(__builtin_amdgcn_sqrtf(q), s, 1.f));
    return nb;
}

struct ConeShared {                      // ~10 KB
    float p2b[EE][4][8];                 // p2.w at fg==7 per [row][w][b]
    float outx[EE][4][8];                // out.x at fg==0 per [row][w][b]
    float4 p1if[256];                    // group0's P1[row GR-1] per column
    float4 oif[256];                     // group1's O[row GR]   per column
};

// ---- cone phases (no barriers inside) ----
template<int RG>
__device__ __forceinline__ void publish(int k, float4 (&P1)[GR], float4 (&P2)[GR],
                                        ConeShared& sh, int c, int b, int fg, int w) {
    if (fg == 7) {
        #pragma unroll
        for (int le = 0; le < GR; ++le) {
            const int e = RG * GR + le;
            if (e >= k && e < EE - k) sh.p2b[e][w][b] = P2[le].w;
        }
    }
    if (RG == 0) sh.p1if[c] = P1[GR - 1];
}

template<int RG, bool ELO, bool EHI>
__device__ __forceinline__ void phase_out(
    int k, const float4 (&Xr)[GR],
    float4 (&P0)[GR], float4 (&P1)[GR], float4 (&P2)[GR], float4 (&O)[GR],
    ConeShared& sh, int c, int b, int fg, int w, int f0, int tb) {
    #pragma unroll
    for (int le = 0; le < GR; ++le) {
        const int e = RG * GR + le;
        if (e < k + 1 || e >= EE - k) continue;          // compile-time row kill
        const int t = tb + e;
        if ((ELO && t < 0) || (EHI && t >= TT)) continue;
        const float4 X = Xr[le];
        float4 o;
        o.x = X.x - P0[le].x - P1[le].x - P2[le].x;
        o.y = X.y - P0[le].y - P1[le].y - P2[le].y + P2[le].x;
        o.z = X.z - P0[le].z - P1[le].z - P2[le].z + P2[le].y;
        o.w = X.w - P0[le].w - P1[le].w - P2[le].w + P2[le].z;
        float4 h0 = shfl_up4(P0[le], 1);                 // p0 at b-1
        if (b > 0) { o.x += h0.x; o.y += h0.y; o.z += h0.z; o.w += h0.w; }
        float4 pm1 = (le > 0) ? P1[le - 1] : sh.p1if[c]; // p1 at t-1 (LDS only RG1,le0)
        if (!ELO || t > 0) { o.x += pm1.x; o.y += pm1.y; o.z += pm1.z; o.w += pm1.w; }
        float pw = __shfl_up(P2[le].w, 8);               // p2.w at f0-4
        if (fg == 0) pw = (w > 0) ? sh.p2b[e][(w - 1)][b] : 0.0f;
        if (f0 > 0) o.x += pw;
        O[le] = o;
        if (fg == 0) sh.outx[e][w][b] = o.x;
    }
}

template<int RG, bool ELO, bool EHI>
__device__ __forceinline__ void phase_upd(
    int k, float4 (&P0)[GR], float4 (&P1)[GR], float4 (&P2)[GR], float4 (&O)[GR],
    ConeShared& sh, int c, int b, int fg, int w, int f0, int tb, float s) {
    #pragma unroll
    for (int le = 0; le < GR; ++le) {
        const int e = RG * GR + le;
        if (e < k + 1 || e > EE - 2 - k) continue;       // compile-time row kill
        const int t = tb + e;
        if ((ELO && t < 0) || (EHI && t >= TT)) continue;
        const float4 cc = O[le];
        const float4 on = (le < GR - 1) ? O[le + 1] : sh.oif[c];  // oif only RG0,le=GR-1
        float4 gT = f4z();
        if (!EHI || t < TT - 1) gT = sub4(on, cc);
        const float4 nB = shfl_dn4(cc, 1);               // out at b+1
        float4 gB = f4z();
        if (b < BB - 1) gB = sub4(nB, cc);
        float nxx = __shfl_down(cc.x, 8);                // out.x at f0+4
        if (fg == 7) nxx = (w < 3) ? sh.outx[e][w + 1][b] : 0.0f;
        float4 gF;
        gF.x = cc.y - cc.x;
        gF.y = cc.z - cc.y;
        gF.z = cc.w - cc.z;
        gF.w = (f0 < FF - 4) ? (nxx - cc.w) : 0.f;
        const float4 nb = nbvec(gB, gT, gF, s);
        P0[le].x = fmaf(-TAU, gB.x, P0[le].x) * nb.x;
        P0[le].y = fmaf(-TAU, gB.y, P0[le].y) * nb.y;
        P0[le].z = fmaf(-TAU, gB.z, P0[le].z) * nb.z;
        P0[le].w = fmaf(-TAU, gB.w, P0[le].w) * nb.w;
        P1[le].x = fmaf(-TAU, gT.x, P1[le].x) * nb.x;
        P1[le].y = fmaf(-TAU, gT.y, P1[le].y) * nb.y;
        P1[le].z = fmaf(-TAU, gT.z, P1[le].z) * nb.z;
        P1[le].w = fmaf(-TAU, gT.w, P1[le].w) * nb.w;
        P2[le].x = fmaf(-TAU, gF.x, P2[le].x) * nb.x;
        P2[le].y = fmaf(-TAU, gF.y, P2[le].y) * nb.y;
        P2[le].z = fmaf(-TAU, gF.z, P2[le].z) * nb.z;
        P2[le].w = fmaf(-TAU, gF.w, P2[le].w) * nb.w;
    }
}

// barriers live here, block-uniform; rg branches wrap only barrier-free compute
template<bool ELO, bool EHI>
__device__ __forceinline__ void cone_run(
    const float4 (&Xr)[GR],
    float4 (&P0)[GR], float4 (&P1)[GR], float4 (&P2)[GR], float4 (&O)[GR],
    ConeShared& sh, int rg, int c, int b, int fg, int w, int f0, int tb, float s) {
    #pragma unroll
    for (int k = 0; k < HH; ++k) {
        if (rg == 0) publish<0>(k, P1, P2, sh, c, b, fg, w);
        else         publish<1>(k, P1, P2, sh, c, b, fg, w);
        __syncthreads();
        if (rg == 0) phase_out<0, ELO, EHI>(k, Xr, P0, P1, P2, O, sh, c, b, fg, w, f0, tb);
        else         phase_out<1, ELO, EHI>(k, Xr, P0, P1, P2, O, sh, c, b, fg, w, f0, tb);
        if (rg == 1) sh.oif[c] = O[0];                   // out at row GR
        __syncthreads();
        if (rg == 0) phase_upd<0, ELO, EHI>(k, P0, P1, P2, O, sh, c, b, fg, w, f0, tb, s);
        else         phase_upd<1, ELO, EHI>(k, P0, P1, P2, O, sh, c, b, fg, w, f0, tb, s);
    }
}

// ==================== mid launch: 4 cone iterations (fp16 p in/out) ====================
template<bool ELO, bool EHI>
__device__ __forceinline__ void mid_main(
    const float* __restrict__ x, const __half* __restrict__ pin, __half* __restrict__ pout,
    ConeShared& sh, int rg, int c, int b, int fg, int w, int f0, int tb, int e0,
    int base, float s) {
    float4 P0[GR], P1[GR], P2[GR], O[GR], Xr[GR];
    #pragma unroll
    for (int le = 0; le < GR; ++le) {
        const int t = tb + e0 + le;
        const bool ok = (!ELO || t >= 0) && (!EHI || t < TT);
        const bool trim = (rg == 0 && le == 0);          // row 0: only P1 ever read
        if (ok) {
            const int v = base + t * ST;
            P1[le] = ld4h(pin + NV + v);
            if (!trim) {
                P0[le] = ld4h(pin + v);
                P2[le] = ld4h(pin + 2 * NV + v);
                Xr[le] = ld4(x + v);
            } else { P0[le] = f4z(); P2[le] = f4z(); Xr[le] = f4z(); }
        } else {
            P0[le] = f4z(); P1[le] = f4z(); P2[le] = f4z(); Xr[le] = f4z();
        }
        O[le] = f4z();
    }
    cone_run<ELO, EHI>(Xr, P0, P1, P2, O, sh, rg, c, b, fg, w, f0, tb, s);
    #pragma unroll
    for (int le = 0; le < GR; ++le) {
        const int e = e0 + le;
        if (e >= HH && e < HH + RR) {                    // owned rows: t always valid
            const int v = base + (tb + e) * ST;
            st4h(pout + v, P0[le]);
            st4h(pout + NV + v, P1[le]);
            st4h(pout + 2 * NV + v, P2[le]);
        }
    }
}

__global__ __launch_bounds__(512, 2)
void k_mid(const float* __restrict__ x, const __half* __restrict__ pin,
           __half* __restrict__ pout, const float* __restrict__ lam) {
    __shared__ ConeShared sh;
    const int tid = threadIdx.x;
    const int blk = blockIdx.x;
    const int rg  = tid >> 8;
    const int c   = tid & 255;
    const int b   = tid & 7;
    const int fg  = (tid >> 3) & 7;
    const int w   = (tid >> 6) & 3;
    const int f0  = w * 32 + fg * 4;
    const int tb  = blk * RR - HH;
    const int e0  = rg * GR;
    const int base = b * SB + f0;
    const float s = TAU / lam[0];
    if (blk == 0 || blk == NBLK - 1)
        mid_main<true, true>(x, pin, pout, sh, rg, c, b, fg, w, f0, tb, e0, base, s);
    else
        mid_main<false, false>(x, pin, pout, sh, rg, c, b, fg, w, f0, tb, e0, base, s);
}

// ============ first launch: iter 1 from p==0 (out==x) + 4 cone iters ============
template<bool ELO, bool EHI>
__device__ __forceinline__ void first_main(
    const float* __restrict__ x, __half* __restrict__ pout,
    ConeShared& sh, int rg, int c, int b, int fg, int w, int f0, int tb, int e0,
    int base, float s) {
    float4 P0[GR], P1[GR], P2[GR], O[GR], Xr[GR], XHa;
    #pragma unroll
    for (int le = 0; le < GR; ++le) {
        const int t = tb + e0 + le;
        const bool ok = (!ELO || t >= 0) && (!EHI || t < TT);
        Xr[le] = ok ? ld4(x + base + t * ST) : f4z();
        O[le] = f4z();
    }
    {
        const int t = tb + e0 + GR;
        const bool ok = (!ELO || t >= 0) && (t < TT);
        XHa = ok ? ld4(x + base + t * ST) : f4z();
    }
    // iteration 1: p = -TAU*grad(x) / (|grad(x)|*s + 1) on all valid rows
    #pragma unroll
    for (int le = 0; le < GR; ++le) {
        const int t = tb + e0 + le;
        if ((!ELO || t >= 0) && (!EHI || t < TT)) {
            const float4 cc = Xr[le];
            const float4 nxt = (le < GR - 1) ? Xr[le + 1] : XHa;
            float4 gT = f4z();
            if (t < TT - 1) gT = sub4(nxt, cc);
            const float4 nB = shfl_dn4(cc, 1);
            float4 gB = f4z();
            if (b < BB - 1) gB = sub4(nB, cc);
            float4 gF;
            gF.x = cc.y - cc.x;
            gF.y = cc.z - cc.y;
            gF.z = cc.w - cc.z;
            gF.w = (f0 < FF - 4) ? (x[base + t * ST + 4] - cc.w) : 0.f;
            const float4 nb = nbvec(gB, gT, gF, s);
            P0[le] = make_float4(-TAU * gB.x * nb.x, -TAU * gB.y * nb.y,
                                 -TAU * gB.z * nb.z, -TAU * gB.w * nb.w);
            P1[le] = make_float4(-TAU * gT.x * nb.x, -TAU * gT.y * nb.y,
                                 -TAU * gT.z * nb.z, -TAU * gT.w * nb.w);
            P2[le] = make_float4(-TAU * gF.x * nb.x, -TAU * gF.y * nb.y,
                                 -TAU * gF.z * nb.z, -TAU * gF.w * nb.w);
        } else {
            P0[le] = f4z(); P1[le] = f4z(); P2[le] = f4z();
        }
    }
    cone_run<ELO, EHI>(Xr, P0, P1, P2, O, sh, rg, c, b, fg, w, f0, tb, s);
    #pragma unroll
    for (int le = 0; le < GR; ++le) {
        const int e = e0 + le;
        if (e >= HH && e < HH + RR) {
            const int v = base + (tb + e) * ST;
            st4h(pout + v, P0[le]);
            st4h(pout + NV + v, P1[le]);
            st4h(pout + 2 * NV + v, P2[le]);
        }
    }
}

__global__ __launch_bounds__(512, 2)
void k_first(const float* __restrict__ x, __half* __restrict__ pout,
             const float* __restrict__ lam) {
    __shared__ ConeShared sh;
    const int tid = threadIdx.x;
    const int blk = blockIdx.x;
    const int rg  = tid >> 8;
    const int c   = tid & 255;
    const int b   = tid & 7;
    const int fg  = (tid >> 3) & 7;
    const int w   = (tid >> 6) & 3;
    const int f0  = w * 32 + fg * 4;
    const int tb  = blk * RR - HH;
    const int e0  = rg * GR;
    const int base = b * SB + f0;
    const float s = TAU / lam[0];
    if (blk == 0 || blk == NBLK - 1)
        first_main<true, true>(x, pout, sh, rg, c, b, fg, w, f0, tb, e0, base, s);
    else
        first_main<false, false>(x, pout, sh, rg, c, b, fg, w, f0, tb, e0, base, s);
}

// ---- final: out = x + div(p) + bias (fp16 p) ----
__global__ __launch_bounds__(256)
void k_final(const float* __restrict__ x, const __half* __restrict__ pin,
             const float* __restrict__ bias, float* __restrict__ out) {
    const int gid = blockIdx.x * 256 + threadIdx.x;
    const int v = gid * 4;
    const int f0 = v & (FF - 1);
    const int t = (v >> 7) & (TT - 1);
    const int b = v >> 18;
    const __half* p0 = pin;
    const __half* p1 = pin + NV;
    const __half* p2 = pin + 2 * NV;
    float4 X = ld4(x + v);
    float4 a0 = ld4h(p0 + v), a1 = ld4h(p1 + v), a2 = ld4h(p2 + v);
    float ox = X.x - a0.x - a1.x - a2.x;
    float oy = X.y - a0.y - a1.y - a2.y + a2.x;
    float oz = X.z - a0.z - a1.z - a2.z + a2.y;
    float ow = X.w - a0.w - a1.w - a2.w + a2.z;
    if (b > 0) { float4 h = ld4h(p0 + v - SB); ox += h.x; oy += h.y; oz += h.z; ow += h.w; }
    if (t > 0) { float4 h = ld4h(p1 + v - ST); ox += h.x; oy += h.y; oz += h.z; ow += h.w; }
    if (f0 > 0) ox += __half2float(p2[v - 1]);
    float4 bi = ld4(bias + f0);
    st4(out + v, make_float4(ox + bi.x, oy + bi.y, oz + bi.z, ow + bi.w));
}

extern "C" void kernel_launch(void* const* d_in, const int* in_sizes, int n_in,
                              void* d_out, int out_size, void* d_ws, size_t ws_size,
                              hipStream_t stream) {
    const float* x    = (const float*)d_in[0];
    const float* lam  = (const float*)d_in[1];
    const float* bias = (const float*)d_in[2];
    float* out = (float*)d_out;

    __half* pA = (__half*)d_ws;                   // 3*NV halfs = 12.6 MB
    __half* pB = pA + 3 * NV;

    // iterations 1..5 (iter-1 specialization + 4 cone iters)
    k_first<<<NBLK, 512, 0, stream>>>(x, pA, lam);
    // iterations 6..29: 6 launches x 4
    __half* pin = pA;
    __half* pout = pB;
    for (int i = 0; i < 6; ++i) {
        k_mid<<<NBLK, 512, 0, stream>>>(x, pin, pout, lam);
        __half* tmp = pin; pin = pout; pout = tmp;
    }
    k_final<<<NV / 1024, 256, 0, stream>>>(x, pin, bias, out);
}